// Round 1
// baseline (658.681 us; speedup 1.0000x reference)
//
#include <hip/hip_runtime.h>
#include <hip/hip_bf16.h>

#define NB 4096
#define PLEN 14
#define NROWS (NB*PLEN)   // 57344
#define BN_EPS 1e-5f

typedef __bf16 bf16x8 __attribute__((ext_vector_type(8)));
typedef float  f32x4  __attribute__((ext_vector_type(4)));

// ---------------- Layer 1: fp32 vector (din=3), agg(x) @ W1 + b1, stats ----
__global__ __launch_bounds__(256) void l1_kernel(
    const float* __restrict__ x,     // [NB][3][PLEN]
    const float* __restrict__ W,     // [3][64]
    const float* __restrict__ bias,  // [64]
    float* __restrict__ pre,         // [NROWS][64]
    float* __restrict__ stats)       // [2048]
{
    const int col  = threadIdx.x & 63;
    const int sub  = threadIdx.x >> 6;            // chain-in-block 0..3
    const int chain = blockIdx.x * 4 + sub;       // 0..4095
    const float w0 = W[0*64+col], w1 = W[1*64+col], w2 = W[2*64+col];
    const float bb = bias[col];
    const float* xb = x + chain*3*PLEN;
    float s = 0.f, s2 = 0.f;
    for (int p = 0; p < PLEN; p++) {
        float u0 = 0.f, u1 = 0.f, u2 = 0.f;
        if (p > 0)      { u0 += xb[p-1]; u1 += xb[PLEN+p-1]; u2 += xb[2*PLEN+p-1]; }
        if (p < PLEN-1) { u0 += xb[p+1]; u1 += xb[PLEN+p+1]; u2 += xb[2*PLEN+p+1]; }
        float v = u0*w0 + u1*w1 + u2*w2 + bb;
        pre[(chain*PLEN + p)*64 + col] = v;
        s += v; s2 += v*v;
    }
    __shared__ float ss[4][64], ssq[4][64];
    ss[sub][col] = s; ssq[sub][col] = s2;
    __syncthreads();
    if (sub == 0) {
        float ts  = ss[0][col]+ss[1][col]+ss[2][col]+ss[3][col];
        float ts2 = ssq[0][col]+ssq[1][col]+ssq[2][col]+ssq[3][col];
        atomicAdd(&stats[col], ts);
        atomicAdd(&stats[1024+col], ts2);
    }
}

// ---------------- prep: BN(prev)+ReLU+chain_agg -> u (bf16) ----------------
template<int D>
__global__ __launch_bounds__(256) void prep_kernel(
    const float* __restrict__ pre,   // [NROWS][D]
    const float* __restrict__ stats, // [2048] sums of pre
    const float* __restrict__ gamma,
    const float* __restrict__ beta,
    __bf16* __restrict__ u)          // [NROWS][D]
{
    int idx = blockIdx.x*256 + threadIdx.x;
    if (idx >= NROWS*D) return;
    int k = idx & (D-1);
    int r = idx / D;
    int p = r % PLEN;
    float mu  = stats[k] * (1.0f/NROWS);
    float var = stats[1024+k] * (1.0f/NROWS) - mu*mu;
    float a = gamma[k] * rsqrtf(var + BN_EPS);
    float c = beta[k] - mu*a;
    float acc = 0.f;
    if (p > 0)       acc += fmaxf(a*pre[idx - D] + c, 0.f);
    if (p < PLEN-1)  acc += fmaxf(a*pre[idx + D] + c, 0.f);
    u[idx] = (__bf16)acc;
}

// ---------------- W convert: [K][Nout] fp32 -> [Nout][K] bf16 --------------
__global__ void wconv_kernel(const float* __restrict__ W, __bf16* __restrict__ Wt,
                             int K, int Nout)
{
    int idx = blockIdx.x*256 + threadIdx.x;
    if (idx >= K*Nout) return;
    int n = idx / K, k = idx - n*K;
    Wt[idx] = (__bf16)W[k*Nout + n];
}

// ---------------- bf16 MFMA GEMM: pre = u @ W + b, stats; L5: chain min/max
template<int K, bool MINMAX>
__global__ __launch_bounds__(256) void gemm_kernel(
    const __bf16* __restrict__ u,    // [NROWS][K]
    const __bf16* __restrict__ wt,   // [Nout][K]
    const float* __restrict__ bias, int Nout,
    float* __restrict__ pre,         // [NROWS][Nout] (if !MINMAX)
    float* __restrict__ omax,        // [NB][Nout]    (if MINMAX)
    float* __restrict__ omin,
    float* __restrict__ stats)       // [2048]
{
    static_assert(K % 32 == 0, "");
    constexpr int KP = K + 8;                 // +8 bf16 pad: breaks 256B-stride conflicts
    __shared__ __align__(16) short su[112*KP];
    __shared__ __align__(16) short swt[64*KP];
    const int tid  = threadIdx.x;
    const int wave = tid >> 6;
    const int lane = tid & 63;
    const int rowbase = blockIdx.x * 112;     // 8 chains
    const int colbase = blockIdx.y * 64;

    for (int i = tid; i < 112*(K/8); i += 256) {
        int r = i / (K/8), kk = (i - r*(K/8))*8;
        *reinterpret_cast<uint4*>(&su[r*KP + kk]) =
            *reinterpret_cast<const uint4*>(u + (size_t)(rowbase + r)*K + kk);
    }
    for (int i = tid; i < 64*(K/8); i += 256) {
        int n = i / (K/8), kk = (i - n*(K/8))*8;
        *reinterpret_cast<uint4*>(&swt[n*KP + kk]) =
            *reinterpret_cast<const uint4*>(wt + (size_t)(colbase + n)*K + kk);
    }
    __syncthreads();

    const int m    = lane & 15;               // A-row / B-col / D-col
    const int koff = (lane >> 4) * 8;         // quad*8
    f32x4 acc[7];
    #pragma unroll
    for (int i = 0; i < 7; i++) acc[i] = (f32x4){0.f,0.f,0.f,0.f};

    #pragma unroll
    for (int ks = 0; ks < K; ks += 32) {
        bf16x8 bfrag = *reinterpret_cast<const bf16x8*>(&swt[(wave*16 + m)*KP + ks + koff]);
        #pragma unroll
        for (int mt = 0; mt < 7; mt++) {
            bf16x8 afrag = *reinterpret_cast<const bf16x8*>(&su[(mt*16 + m)*KP + ks + koff]);
            acc[mt] = __builtin_amdgcn_mfma_f32_16x16x32_bf16(afrag, bfrag, acc[mt], 0, 0, 0);
        }
    }

    const int ocol = colbase + wave*16 + m;
    const float bb = bias[ocol];
    const int r0 = (lane >> 4) * 4;
    float s = 0.f, s2 = 0.f;

    if constexpr (!MINMAX) {
        #pragma unroll
        for (int mt = 0; mt < 7; mt++)
            #pragma unroll
            for (int r = 0; r < 4; r++) {
                float v = acc[mt][r] + bb;
                pre[(size_t)(rowbase + mt*16 + r0 + r)*Nout + ocol] = v;
                s += v; s2 += v*v;
            }
    } else {
        #pragma unroll
        for (int mt = 0; mt < 7; mt++)
            #pragma unroll
            for (int r = 0; r < 4; r++) { float v = acc[mt][r] + bb; s += v; s2 += v*v; }
    }
    // lanes sharing ocol differ in bits 4/5 of lane
    s  += __shfl_xor(s, 16);  s  += __shfl_xor(s, 32);
    s2 += __shfl_xor(s2, 16); s2 += __shfl_xor(s2, 32);
    if (lane < 16) {
        atomicAdd(&stats[ocol], s);
        atomicAdd(&stats[1024 + ocol], s2);
    }

    if constexpr (MINMAX) {
        __syncthreads();                       // all su reads done before overwrite
        float* tile = reinterpret_cast<float*>(su);   // [112][65] fits in su (30464B)
        #pragma unroll
        for (int mt = 0; mt < 7; mt++)
            #pragma unroll
            for (int r = 0; r < 4; r++)
                tile[(mt*16 + r0 + r)*65 + wave*16 + m] = acc[mt][r] + bb;
        __syncthreads();
        for (int i = tid; i < 8*64; i += 256) {
            int ch = i >> 6, c = i & 63;
            float mx = -3.4e38f, mn = 3.4e38f;
            #pragma unroll
            for (int p = 0; p < PLEN; p++) {
                float v = tile[(ch*PLEN + p)*65 + c];
                mx = fmaxf(mx, v); mn = fminf(mn, v);
            }
            int chain = blockIdx.x*8 + ch;
            omax[(size_t)chain*Nout + colbase + c] = mx;
            omin[(size_t)chain*Nout + colbase + c] = mn;
        }
    }
}

// ---------------- head: BN5+ReLU on chain-max/min, emb matmul --------------
__global__ __launch_bounds__(256) void head_kernel(
    const float* __restrict__ omax, const float* __restrict__ omin,
    const float* __restrict__ stats,
    const float* __restrict__ gamma, const float* __restrict__ beta,
    const float* __restrict__ embW,  // [1024][10]
    const float* __restrict__ embB,  // [10]
    float* __restrict__ e)           // [NB][10]
{
    const int wave = threadIdx.x >> 6, lane = threadIdx.x & 63;
    const int b = blockIdx.x*4 + wave;
    float acc[10];
    #pragma unroll
    for (int j = 0; j < 10; j++) acc[j] = 0.f;
    for (int k = lane; k < 1024; k += 64) {
        float mu  = stats[k] * (1.0f/NROWS);
        float var = stats[1024+k] * (1.0f/NROWS) - mu*mu;
        float a = gamma[k] * rsqrtf(var + BN_EPS);
        float c = beta[k] - mu*a;
        float v = (a >= 0.f) ? omax[(size_t)b*1024 + k] : omin[(size_t)b*1024 + k];
        float h = fmaxf(a*v + c, 0.f);
        #pragma unroll
        for (int j = 0; j < 10; j++) acc[j] += h * embW[k*10 + j];
    }
    #pragma unroll
    for (int j = 0; j < 10; j++) {
        acc[j] += __shfl_down(acc[j], 32);
        acc[j] += __shfl_down(acc[j], 16);
        acc[j] += __shfl_down(acc[j], 8);
        acc[j] += __shfl_down(acc[j], 4);
        acc[j] += __shfl_down(acc[j], 2);
        acc[j] += __shfl_down(acc[j], 1);
    }
    if (lane == 0) {
        #pragma unroll
        for (int j = 0; j < 10; j++) e[b*10 + j] = acc[j] + embB[j];
    }
}

// ---------------- cluster: d, q=1/(1+d) row-normalized; optional sim -------
__global__ __launch_bounds__(256) void cluster_kernel(
    const float* __restrict__ e,       // this input's e [NB][10]
    const float* __restrict__ cluW,    // [800][10]
    float* __restrict__ cOut,          // [NB][800]
    float* __restrict__ dOut,          // [NB][800] or null
    const float* __restrict__ eOther,  // e1 (for sim) or null
    float* __restrict__ simOut)        // [NB] or null
{
    const int b = blockIdx.x, tid = threadIdx.x;
    const int wave = tid >> 6, lane = tid & 63;
    __shared__ float se[10];
    if (tid < 10) se[tid] = e[b*10 + tid];
    __syncthreads();
    float ev[10];
    #pragma unroll
    for (int j = 0; j < 10; j++) ev[j] = se[j];
    float dloc[4], qloc[4], qs = 0.f;
    #pragma unroll
    for (int i = 0; i < 4; i++) {
        int mm = tid + i*256;
        float dd = 0.f;
        if (mm < 800) {
            #pragma unroll
            for (int j = 0; j < 10; j++) { float t = ev[j] - cluW[mm*10 + j]; dd += t*t; }
        }
        dloc[i] = dd;
        float q = (mm < 800) ? 1.f/(1.f + dd) : 0.f;
        qloc[i] = q; qs += q;
    }
    float t = qs;
    t += __shfl_down(t,32); t += __shfl_down(t,16); t += __shfl_down(t,8);
    t += __shfl_down(t,4);  t += __shfl_down(t,2);  t += __shfl_down(t,1);
    __shared__ float sred[4];
    if (lane == 0) sred[wave] = t;
    __syncthreads();
    float inv = 1.f / (sred[0]+sred[1]+sred[2]+sred[3]);
    #pragma unroll
    for (int i = 0; i < 4; i++) {
        int mm = tid + i*256;
        if (mm < 800) {
            cOut[(size_t)b*800 + mm] = qloc[i]*inv;
            if (dOut) dOut[(size_t)b*800 + mm] = dloc[i];
        }
    }
    if (simOut && tid == 0) {
        float ss = 0.f;
        #pragma unroll
        for (int j = 0; j < 10; j++) {
            float df = eOther[b*10 + j] - se[j] + 1e-6f;   // e1 - e2 + eps
            ss += df*df;
        }
        simOut[b] = sqrtf(ss);
    }
}

// ---------------------------------------------------------------------------
extern "C" void kernel_launch(void* const* d_in, const int* in_sizes, int n_in,
                              void* d_out, int out_size, void* d_ws, size_t ws_size,
                              hipStream_t stream)
{
    const float* x[2] = {(const float*)d_in[0], (const float*)d_in[1]};
    const float *W[5], *bi[5], *ga[5], *be[5];
    for (int l = 0; l < 5; l++) {
        W[l]  = (const float*)d_in[2 + 4*l];
        bi[l] = (const float*)d_in[3 + 4*l];
        ga[l] = (const float*)d_in[4 + 4*l];
        be[l] = (const float*)d_in[5 + 4*l];
    }
    const float* embW = (const float*)d_in[22];
    const float* embB = (const float*)d_in[23];
    const float* cluW = (const float*)d_in[24];
    float* out = (float*)d_out;
    float* ws  = (float*)d_ws;

    // workspace layout (floats): total ~78 MB
    float*  pre   = ws;                                     // NROWS*128
    __bf16* ubuf  = (__bf16*)(ws + 7340032);                // NROWS*128 bf16
    float*  omax  = ws + 11010048;                          // NB*1024
    float*  omin  = ws + 15204352;                          // NB*1024
    float*  stats = ws + 19398656;                          // 10*2048
    __bf16* wt    = (__bf16*)(ws + 19419136);               // 147456 bf16
    __bf16* wt2 = wt, *wt3 = wt + 4096, *wt4 = wt + 8192, *wt5 = wt + 16384;

    hipMemsetAsync(stats, 0, 10*2048*sizeof(float), stream);

    wconv_kernel<<<(64*64+255)/256,   256, 0, stream>>>(W[1], wt2, 64, 64);
    wconv_kernel<<<(64*64+255)/256,   256, 0, stream>>>(W[2], wt3, 64, 64);
    wconv_kernel<<<(64*128+255)/256,  256, 0, stream>>>(W[3], wt4, 64, 128);
    wconv_kernel<<<(128*1024+255)/256,256, 0, stream>>>(W[4], wt5, 128, 1024);

    float* simO = out;
    float* c1O  = out + 4096;
    float* c2O  = out + 3280896;
    float* e1O  = out + 6557696;
    float* e2O  = out + 6598656;
    float* d1O  = out + 6639616;

    for (int inp = 0; inp < 2; inp++) {
        float* st = stats + inp*5*2048;
        l1_kernel<<<NB/4, 256, 0, stream>>>(x[inp], W[0], bi[0], pre, st);
        prep_kernel<64><<<NROWS*64/256, 256, 0, stream>>>(pre, st, ga[0], be[0], ubuf);
        gemm_kernel<64,false><<<dim3(NROWS/112,1), 256, 0, stream>>>(
            ubuf, wt2, bi[1], 64, pre, nullptr, nullptr, st + 2048);
        prep_kernel<64><<<NROWS*64/256, 256, 0, stream>>>(pre, st + 2048, ga[1], be[1], ubuf);
        gemm_kernel<64,false><<<dim3(NROWS/112,1), 256, 0, stream>>>(
            ubuf, wt3, bi[2], 64, pre, nullptr, nullptr, st + 4096);
        prep_kernel<64><<<NROWS*64/256, 256, 0, stream>>>(pre, st + 4096, ga[2], be[2], ubuf);
        gemm_kernel<64,false><<<dim3(NROWS/112,2), 256, 0, stream>>>(
            ubuf, wt4, bi[3], 128, pre, nullptr, nullptr, st + 6144);
        prep_kernel<128><<<NROWS*128/256, 256, 0, stream>>>(pre, st + 6144, ga[3], be[3], ubuf);
        gemm_kernel<128,true><<<dim3(NROWS/112,16), 256, 0, stream>>>(
            ubuf, wt5, bi[4], 1024, nullptr, omax, omin, st + 8192);
        float* eO = (inp == 0) ? e1O : e2O;
        head_kernel<<<NB/4, 256, 0, stream>>>(omax, omin, st + 8192, ga[4], be[4],
                                              embW, embB, eO);
        cluster_kernel<<<NB, 256, 0, stream>>>(
            eO, cluW,
            (inp == 0) ? c1O : c2O,
            (inp == 0) ? d1O : nullptr,
            (inp == 0) ? nullptr : e1O,
            (inp == 0) ? nullptr : simO);
    }
}

// Round 2
// 622.461 us; speedup vs baseline: 1.0582x; 1.0582x over previous
//
#include <hip/hip_runtime.h>
#include <hip/hip_bf16.h>

#define NB 4096
#define PLEN 14
#define NROWS (NB*PLEN)   // 57344
#define BN_EPS 1e-5f

typedef __bf16 bf16x8 __attribute__((ext_vector_type(8)));
typedef float  f32x4  __attribute__((ext_vector_type(4)));

typedef const __attribute__((address_space(1))) char* gas_cp;
typedef __attribute__((address_space(3))) char* las_p;

__device__ __forceinline__ void gl_lds16(const void* g, void* l) {
    __builtin_amdgcn_global_load_lds((gas_cp)g, (las_p)l, 16, 0, 0);
}

// ---------------- Layer 1: fp32 vector (din=3), agg(x) @ W1 + b1, stats ----
__global__ __launch_bounds__(256) void l1_kernel(
    const float* __restrict__ x,     // [NB][3][PLEN]
    const float* __restrict__ W,     // [3][64]
    const float* __restrict__ bias,  // [64]
    float* __restrict__ pre,         // [NROWS][64]
    float* __restrict__ stats)       // [2048]
{
    const int col  = threadIdx.x & 63;
    const int sub  = threadIdx.x >> 6;            // chain-in-block 0..3
    const int chain = blockIdx.x * 4 + sub;       // 0..4095
    const float w0 = W[0*64+col], w1 = W[1*64+col], w2 = W[2*64+col];
    const float bb = bias[col];
    const float* xb = x + chain*3*PLEN;
    float s = 0.f, s2 = 0.f;
    for (int p = 0; p < PLEN; p++) {
        float u0 = 0.f, u1 = 0.f, u2 = 0.f;
        if (p > 0)      { u0 += xb[p-1]; u1 += xb[PLEN+p-1]; u2 += xb[2*PLEN+p-1]; }
        if (p < PLEN-1) { u0 += xb[p+1]; u1 += xb[PLEN+p+1]; u2 += xb[2*PLEN+p+1]; }
        float v = u0*w0 + u1*w1 + u2*w2 + bb;
        pre[(chain*PLEN + p)*64 + col] = v;
        s += v; s2 += v*v;
    }
    __shared__ float ss[4][64], ssq[4][64];
    ss[sub][col] = s; ssq[sub][col] = s2;
    __syncthreads();
    if (sub == 0) {
        float ts  = ss[0][col]+ss[1][col]+ss[2][col]+ss[3][col];
        float ts2 = ssq[0][col]+ssq[1][col]+ssq[2][col]+ssq[3][col];
        atomicAdd(&stats[col], ts);
        atomicAdd(&stats[1024+col], ts2);
    }
}

// ---------------- prep: BN(prev)+ReLU+chain_agg -> u (bf16, stride OS) -----
template<int D, int OS>
__global__ __launch_bounds__(256) void prep_kernel(
    const float* __restrict__ pre,   // [NROWS][D]
    const float* __restrict__ stats, // [2048] sums of pre
    const float* __restrict__ gamma,
    const float* __restrict__ beta,
    __bf16* __restrict__ u)          // [NROWS][OS]
{
    int idx = blockIdx.x*256 + threadIdx.x;
    if (idx >= NROWS*D) return;
    int k = idx & (D-1);
    int r = idx / D;
    int p = r % PLEN;
    float mu  = stats[k] * (1.0f/NROWS);
    float var = stats[1024+k] * (1.0f/NROWS) - mu*mu;
    float a = gamma[k] * rsqrtf(var + BN_EPS);
    float c = beta[k] - mu*a;
    float acc = 0.f;
    if (p > 0)       acc += fmaxf(a*pre[idx - D] + c, 0.f);
    if (p < PLEN-1)  acc += fmaxf(a*pre[idx + D] + c, 0.f);
    u[(size_t)r*OS + k] = (__bf16)acc;
}

// ---------------- W convert: [K][Nout] fp32 -> [Nout][K] bf16 --------------
__global__ void wconv_kernel(const float* __restrict__ W, __bf16* __restrict__ Wt,
                             int K, int Nout)
{
    int idx = blockIdx.x*256 + threadIdx.x;
    if (idx >= K*Nout) return;
    int n = idx / K, k = idx - n*K;
    Wt[idx] = (__bf16)W[k*Nout + n];
}

// ---------------- W5 convert to blocked layout [16 c][16 kg][64 n][8 kk] ---
__global__ void wconv5_kernel(const float* __restrict__ W,  // [128][1024]
                              __bf16* __restrict__ out)     // 131072
{
    int o = blockIdx.x*256 + threadIdx.x;
    int kk = o & 7, n = (o >> 3) & 63, kg = (o >> 9) & 15, c = o >> 13;
    out[o] = (__bf16)W[(kg*8 + kk)*1024 + c*64 + n];
}

// ---------------- bf16 MFMA GEMM (layers 2-4): pre = u @ W + b, stats ------
template<int K>
__global__ __launch_bounds__(256) void gemm_kernel(
    const __bf16* __restrict__ u,    // [NROWS][K]
    const __bf16* __restrict__ wt,   // [Nout][K]
    const float* __restrict__ bias, int Nout,
    float* __restrict__ pre,         // [NROWS][Nout]
    float* __restrict__ stats)       // [2048]
{
    static_assert(K % 32 == 0, "");
    constexpr int KP = K + 8;
    __shared__ __align__(16) short su[112*KP];
    __shared__ __align__(16) short swt[64*KP];
    const int tid  = threadIdx.x;
    const int wave = tid >> 6;
    const int lane = tid & 63;
    const int rowbase = blockIdx.x * 112;
    const int colbase = blockIdx.y * 64;

    for (int i = tid; i < 112*(K/8); i += 256) {
        int r = i / (K/8), kk = (i - r*(K/8))*8;
        *reinterpret_cast<uint4*>(&su[r*KP + kk]) =
            *reinterpret_cast<const uint4*>(u + (size_t)(rowbase + r)*K + kk);
    }
    for (int i = tid; i < 64*(K/8); i += 256) {
        int n = i / (K/8), kk = (i - n*(K/8))*8;
        *reinterpret_cast<uint4*>(&swt[n*KP + kk]) =
            *reinterpret_cast<const uint4*>(wt + (size_t)(colbase + n)*K + kk);
    }
    __syncthreads();

    const int m    = lane & 15;
    const int koff = (lane >> 4) * 8;
    f32x4 acc[7];
    #pragma unroll
    for (int i = 0; i < 7; i++) acc[i] = (f32x4){0.f,0.f,0.f,0.f};

    #pragma unroll
    for (int ks = 0; ks < K; ks += 32) {
        bf16x8 bfrag = *reinterpret_cast<const bf16x8*>(&swt[(wave*16 + m)*KP + ks + koff]);
        #pragma unroll
        for (int mt = 0; mt < 7; mt++) {
            bf16x8 afrag = *reinterpret_cast<const bf16x8*>(&su[(mt*16 + m)*KP + ks + koff]);
            acc[mt] = __builtin_amdgcn_mfma_f32_16x16x32_bf16(afrag, bfrag, acc[mt], 0, 0, 0);
        }
    }

    const int ocol = colbase + wave*16 + m;
    const float bb = bias[ocol];
    const int r0 = (lane >> 4) * 4;
    float s = 0.f, s2 = 0.f;

    #pragma unroll
    for (int mt = 0; mt < 7; mt++)
        #pragma unroll
        for (int r = 0; r < 4; r++) {
            float v = acc[mt][r] + bb;
            pre[(size_t)(rowbase + mt*16 + r0 + r)*Nout + ocol] = v;
            s += v; s2 += v*v;
        }
    s  += __shfl_xor(s, 16);  s  += __shfl_xor(s, 32);
    s2 += __shfl_xor(s2, 16); s2 += __shfl_xor(s2, 32);
    if (lane < 16) {
        atomicAdd(&stats[ocol], s);
        atomicAdd(&stats[1024 + ocol], s2);
    }
}

// ---------------- Layer 5: register-A, streamed-B GEMM + chain min/max -----
// grid 512 blocks (2/CU, fully resident). A-tile (112x128 bf16, padded to
// stride 136 in global by prep) staged ONCE via global_load_lds; fragments
// held in 112 VGPRs. B (1024x128) pre-blocked as [16 chunks][16 kg][64 n][8 kk]
// and streamed chunk-by-chunk with double-buffered async DMA.
__global__ __launch_bounds__(256, 2) void l5_kernel(
    const __bf16* __restrict__ u,    // [NROWS][136] padded
    const __bf16* __restrict__ wtb,  // blocked, 131072 elems
    const float* __restrict__ bias,  // [1024]
    float* __restrict__ omax,        // [NB][1024]
    float* __restrict__ omin,        // [NB][1024]
    float* __restrict__ stats)       // [2048]
{
    __shared__ __align__(16) short sA[15232];    // 112*136 = 30464 B
    __shared__ __align__(16) short sB[2][8192];  // 2 x 16 KB
    const int tid  = threadIdx.x;
    const int wave = tid >> 6;
    const int lane = tid & 63;
    const int m = lane & 15, q = lane >> 4;
    const int rowbase = blockIdx.x * 112;

    // --- stage A: straight contiguous copy, 1904 16B segments ---
    const char* gA = (const char*)(u + (size_t)rowbase*136);
    for (int i = wave; i < 30; i += 4) {
        int cnt = 1904 - i*64;                  // >=64 except last (48)
        if (lane < cnt)
            gl_lds16(gA + (i*64 + lane)*16, (char*)sA + i*1024);
    }
    // --- stage B chunk 0 ---
    {
        const char* gB = (const char*)wtb;
        #pragma unroll
        for (int s4 = 0; s4 < 4; ++s4) {
            int seg = wave*4 + s4;
            gl_lds16(gB + seg*1024 + lane*16, (char*)sB[0] + seg*1024);
        }
    }
    __syncthreads();

    // --- A fragments -> registers (28 x bf16x8 = 112 VGPR) ---
    bf16x8 af[7][4];
    #pragma unroll
    for (int t = 0; t < 7; ++t)
        #pragma unroll
        for (int kk = 0; kk < 4; ++kk)
            af[t][kk] = *reinterpret_cast<const bf16x8*>(&sA[(t*16 + m)*136 + kk*32 + q*8]);
    __syncthreads();   // all A reads done before sA is reused as epilogue slabs

    float* slab = reinterpret_cast<float*>(sA) + wave*1904;  // [112][17] per wave

    for (int c = 0; c < 16; ++c) {
        if (c < 15) {   // prefetch next B chunk into alternate buffer
            const char* gB = (const char*)wtb + (c+1)*16384;
            char* lB = (char*)sB[(c+1) & 1];
            #pragma unroll
            for (int s4 = 0; s4 < 4; ++s4) {
                int seg = wave*4 + s4;
                gl_lds16(gB + seg*1024 + lane*16, lB + seg*1024);
            }
        }
        const short* bcur = sB[c & 1];
        f32x4 acc[7];
        #pragma unroll
        for (int t = 0; t < 7; ++t) acc[t] = (f32x4){0.f,0.f,0.f,0.f};
        #pragma unroll
        for (int k4 = 0; k4 < 4; ++k4) {
            bf16x8 bf = *reinterpret_cast<const bf16x8*>(
                &bcur[(k4*4 + q)*512 + (wave*16 + m)*8]);
            #pragma unroll
            for (int t = 0; t < 7; ++t)
                acc[t] = __builtin_amdgcn_mfma_f32_16x16x32_bf16(af[t][k4], bf, acc[t], 0, 0, 0);
        }
        const int ocol = c*64 + wave*16 + m;
        const float bb = bias[ocol];
        const int r0 = q*4;
        float s = 0.f, s2 = 0.f;
        #pragma unroll
        for (int t = 0; t < 7; ++t)
            #pragma unroll
            for (int r = 0; r < 4; ++r) {
                float v = acc[t][r] + bb;
                s += v; s2 += v*v;
                slab[(t*16 + r0 + r)*17 + m] = v;
            }
        s  += __shfl_xor(s, 16);  s  += __shfl_xor(s, 32);
        s2 += __shfl_xor(s2, 16); s2 += __shfl_xor(s2, 32);
        if (lane < 16) {
            atomicAdd(&stats[ocol], s);
            atomicAdd(&stats[1024 + ocol], s2);
        }
        __syncthreads();   // waves done reading bcur; prefetch c+1 drained
        // chain min/max from wave-private slab (16 cols x 8 chains)
        #pragma unroll
        for (int pi = 0; pi < 2; ++pi) {
            int ch  = (lane + 64*pi) >> 4;     // 0..7
            int col = lane & 15;
            float mx = -3.4e38f, mn = 3.4e38f;
            #pragma unroll
            for (int p = 0; p < PLEN; ++p) {
                float v = slab[(ch*PLEN + p)*17 + col];
                mx = fmaxf(mx, v); mn = fminf(mn, v);
            }
            size_t off = (size_t)(blockIdx.x*8 + ch)*1024 + (ocol - m + col);
            omax[off] = mx; omin[off] = mn;
        }
    }
}

// ---------------- head: BN5+ReLU on chain-max/min, emb matmul --------------
__global__ __launch_bounds__(256) void head_kernel(
    const float* __restrict__ omax, const float* __restrict__ omin,
    const float* __restrict__ stats,
    const float* __restrict__ gamma, const float* __restrict__ beta,
    const float* __restrict__ embW,  // [1024][10]
    const float* __restrict__ embB,  // [10]
    float* __restrict__ e)           // [NB][10]
{
    const int wave = threadIdx.x >> 6, lane = threadIdx.x & 63;
    const int b = blockIdx.x*4 + wave;
    float acc[10];
    #pragma unroll
    for (int j = 0; j < 10; j++) acc[j] = 0.f;
    for (int k = lane; k < 1024; k += 64) {
        float mu  = stats[k] * (1.0f/NROWS);
        float var = stats[1024+k] * (1.0f/NROWS) - mu*mu;
        float a = gamma[k] * rsqrtf(var + BN_EPS);
        float c = beta[k] - mu*a;
        float v = (a >= 0.f) ? omax[(size_t)b*1024 + k] : omin[(size_t)b*1024 + k];
        float h = fmaxf(a*v + c, 0.f);
        #pragma unroll
        for (int j = 0; j < 10; j++) acc[j] += h * embW[k*10 + j];
    }
    #pragma unroll
    for (int j = 0; j < 10; j++) {
        acc[j] += __shfl_down(acc[j], 32);
        acc[j] += __shfl_down(acc[j], 16);
        acc[j] += __shfl_down(acc[j], 8);
        acc[j] += __shfl_down(acc[j], 4);
        acc[j] += __shfl_down(acc[j], 2);
        acc[j] += __shfl_down(acc[j], 1);
    }
    if (lane == 0) {
        #pragma unroll
        for (int j = 0; j < 10; j++) e[b*10 + j] = acc[j] + embB[j];
    }
}

// ---------------- cluster: d, q=1/(1+d) row-normalized; optional sim -------
__global__ __launch_bounds__(256) void cluster_kernel(
    const float* __restrict__ e,
    const float* __restrict__ cluW,    // [800][10]
    float* __restrict__ cOut,          // [NB][800]
    float* __restrict__ dOut,          // [NB][800] or null
    const float* __restrict__ eOther,  // e1 (for sim) or null
    float* __restrict__ simOut)        // [NB] or null
{
    const int b = blockIdx.x, tid = threadIdx.x;
    const int wave = tid >> 6, lane = tid & 63;
    __shared__ float se[10];
    if (tid < 10) se[tid] = e[b*10 + tid];
    __syncthreads();
    float ev[10];
    #pragma unroll
    for (int j = 0; j < 10; j++) ev[j] = se[j];
    float dloc[4], qloc[4], qs = 0.f;
    #pragma unroll
    for (int i = 0; i < 4; i++) {
        int mm = tid + i*256;
        float dd = 0.f;
        if (mm < 800) {
            #pragma unroll
            for (int j = 0; j < 10; j++) { float t = ev[j] - cluW[mm*10 + j]; dd += t*t; }
        }
        dloc[i] = dd;
        float qv = (mm < 800) ? 1.f/(1.f + dd) : 0.f;
        qloc[i] = qv; qs += qv;
    }
    float t = qs;
    t += __shfl_down(t,32); t += __shfl_down(t,16); t += __shfl_down(t,8);
    t += __shfl_down(t,4);  t += __shfl_down(t,2);  t += __shfl_down(t,1);
    __shared__ float sred[4];
    if (lane == 0) sred[wave] = t;
    __syncthreads();
    float inv = 1.f / (sred[0]+sred[1]+sred[2]+sred[3]);
    #pragma unroll
    for (int i = 0; i < 4; i++) {
        int mm = tid + i*256;
        if (mm < 800) {
            cOut[(size_t)b*800 + mm] = qloc[i]*inv;
            if (dOut) dOut[(size_t)b*800 + mm] = dloc[i];
        }
    }
    if (simOut && tid == 0) {
        float ss = 0.f;
        #pragma unroll
        for (int j = 0; j < 10; j++) {
            float df = eOther[b*10 + j] - se[j] + 1e-6f;
            ss += df*df;
        }
        simOut[b] = sqrtf(ss);
    }
}

// ---------------------------------------------------------------------------
extern "C" void kernel_launch(void* const* d_in, const int* in_sizes, int n_in,
                              void* d_out, int out_size, void* d_ws, size_t ws_size,
                              hipStream_t stream)
{
    const float* x[2] = {(const float*)d_in[0], (const float*)d_in[1]};
    const float *W[5], *bi[5], *ga[5], *be[5];
    for (int l = 0; l < 5; l++) {
        W[l]  = (const float*)d_in[2 + 4*l];
        bi[l] = (const float*)d_in[3 + 4*l];
        ga[l] = (const float*)d_in[4 + 4*l];
        be[l] = (const float*)d_in[5 + 4*l];
    }
    const float* embW = (const float*)d_in[22];
    const float* embB = (const float*)d_in[23];
    const float* cluW = (const float*)d_in[24];
    float* out = (float*)d_out;
    float* ws  = (float*)d_ws;

    // workspace layout (floats): ~79 MB
    float*  pre   = ws;                                     // NROWS*128
    __bf16* ubuf  = (__bf16*)(ws + 7340032);                // NROWS*136 bf16
    float*  omax  = ws + 11239424;                          // NB*1024
    float*  omin  = ws + 15433728;
    float*  stats = ws + 19628032;                          // 10*2048
    __bf16* wt    = (__bf16*)(ws + 19648512);
    __bf16* wt2 = wt, *wt3 = wt + 4096, *wt4 = wt + 8192, *wt5b = wt + 16384;

    hipMemsetAsync(stats, 0, 10*2048*sizeof(float), stream);

    wconv_kernel<<<(64*64+255)/256,   256, 0, stream>>>(W[1], wt2, 64, 64);
    wconv_kernel<<<(64*64+255)/256,   256, 0, stream>>>(W[2], wt3, 64, 64);
    wconv_kernel<<<(64*128+255)/256,  256, 0, stream>>>(W[3], wt4, 64, 128);
    wconv5_kernel<<<131072/256, 256, 0, stream>>>(W[4], wt5b);

    float* simO = out;
    float* c1O  = out + 4096;
    float* c2O  = out + 3280896;
    float* e1O  = out + 6557696;
    float* e2O  = out + 6598656;
    float* d1O  = out + 6639616;

    for (int inp = 0; inp < 2; inp++) {
        float* st = stats + inp*5*2048;
        l1_kernel<<<NB/4, 256, 0, stream>>>(x[inp], W[0], bi[0], pre, st);
        prep_kernel<64,64><<<NROWS*64/256, 256, 0, stream>>>(pre, st, ga[0], be[0], ubuf);
        gemm_kernel<64><<<dim3(NROWS/112,1), 256, 0, stream>>>(
            ubuf, wt2, bi[1], 64, pre, st + 2048);
        prep_kernel<64,64><<<NROWS*64/256, 256, 0, stream>>>(pre, st + 2048, ga[1], be[1], ubuf);
        gemm_kernel<64><<<dim3(NROWS/112,1), 256, 0, stream>>>(
            ubuf, wt3, bi[2], 64, pre, st + 4096);
        prep_kernel<64,64><<<NROWS*64/256, 256, 0, stream>>>(pre, st + 4096, ga[2], be[2], ubuf);
        gemm_kernel<64><<<dim3(NROWS/112,2), 256, 0, stream>>>(
            ubuf, wt4, bi[3], 128, pre, st + 6144);
        prep_kernel<128,136><<<NROWS*128/256, 256, 0, stream>>>(pre, st + 6144, ga[3], be[3], ubuf);
        l5_kernel<<<NROWS/112, 256, 0, stream>>>(ubuf, wt5b, bi[4], omax, omin, st + 8192);
        float* eO = (inp == 0) ? e1O : e2O;
        head_kernel<<<NB/4, 256, 0, stream>>>(omax, omin, st + 8192, ga[4], be[4],
                                              embW, embB, eO);
        cluster_kernel<<<NB, 256, 0, stream>>>(
            eO, cluW,
            (inp == 0) ? c1O : c2O,
            (inp == 0) ? d1O : nullptr,
            (inp == 0) ? nullptr : e1O,
            (inp == 0) ? nullptr : simO);
    }
}

// Round 3
// 432.188 us; speedup vs baseline: 1.5241x; 1.4403x over previous
//
#include <hip/hip_runtime.h>
#include <hip/hip_bf16.h>

#define NB 4096
#define PLEN 14
#define NROWS (NB*PLEN)   // 57344
#define BN_EPS 1e-5f

typedef __bf16 bf16x8 __attribute__((ext_vector_type(8)));
typedef float  f32x4  __attribute__((ext_vector_type(4)));

typedef const __attribute__((address_space(1))) char* gas_cp;
typedef __attribute__((address_space(3))) char* las_p;

__device__ __forceinline__ void gl_lds16(const void* g, void* l) {
    __builtin_amdgcn_global_load_lds((gas_cp)g, (las_p)l, 16, 0, 0);
}

// ---------------- wprep: zero stats + all weight converts in one launch ----
__global__ __launch_bounds__(256) void wprep_kernel(
    const float* __restrict__ W2, const float* __restrict__ W3,
    const float* __restrict__ W4, const float* __restrict__ W5,
    __bf16* __restrict__ wt2, __bf16* __restrict__ wt3,
    __bf16* __restrict__ wt4, __bf16* __restrict__ wt5b,
    float* __restrict__ stats)
{
    int idx = blockIdx.x*256 + threadIdx.x;
    if (idx < 20480) { stats[idx] = 0.f; return; }
    idx -= 20480;
    if (idx < 4096) { int n = idx>>6, k = idx&63; wt2[idx] = (__bf16)W2[k*64+n]; return; }
    idx -= 4096;
    if (idx < 4096) { int n = idx>>6, k = idx&63; wt3[idx] = (__bf16)W3[k*64+n]; return; }
    idx -= 4096;
    if (idx < 8192) { int n = idx>>6, k = idx&63; wt4[idx] = (__bf16)W4[k*128+n]; return; }
    idx -= 8192;
    // W5 blocked: [16 c][16 kg][64 n][8 kk]
    int kk = idx & 7, n = (idx >> 3) & 63, kg = (idx >> 9) & 15, c = idx >> 13;
    wt5b[idx] = (__bf16)W5[(kg*8 + kk)*1024 + c*64 + n];
}

// ---------------- Layer 1: fp32 vector (din=3), agg(x) @ W1 + b1, stats ----
__global__ __launch_bounds__(256) void l1_kernel(
    const float* __restrict__ x,     // [NB][3][PLEN]
    const float* __restrict__ W,     // [3][64]
    const float* __restrict__ bias,  // [64]
    float* __restrict__ pre,         // [NROWS][64]
    float* __restrict__ stats)       // [2048]
{
    const int col  = threadIdx.x & 63;
    const int sub  = threadIdx.x >> 6;
    const int chain = blockIdx.x * 4 + sub;
    const float w0 = W[0*64+col], w1 = W[1*64+col], w2 = W[2*64+col];
    const float bb = bias[col];
    const float* xb = x + chain*3*PLEN;
    float s = 0.f, s2 = 0.f;
    for (int p = 0; p < PLEN; p++) {
        float u0 = 0.f, u1 = 0.f, u2 = 0.f;
        if (p > 0)      { u0 += xb[p-1]; u1 += xb[PLEN+p-1]; u2 += xb[2*PLEN+p-1]; }
        if (p < PLEN-1) { u0 += xb[p+1]; u1 += xb[PLEN+p+1]; u2 += xb[2*PLEN+p+1]; }
        float v = u0*w0 + u1*w1 + u2*w2 + bb;
        pre[(chain*PLEN + p)*64 + col] = v;
        s += v; s2 += v*v;
    }
    __shared__ float ss[4][64], ssq[4][64];
    ss[sub][col] = s; ssq[sub][col] = s2;
    __syncthreads();
    if (sub == 0) {
        float ts  = ss[0][col]+ss[1][col]+ss[2][col]+ss[3][col];
        float ts2 = ssq[0][col]+ssq[1][col]+ssq[2][col]+ssq[3][col];
        atomicAdd(&stats[col], ts);
        atomicAdd(&stats[1024+col], ts2);
    }
}

// ---------------- fused layer (2-4): BN+ReLU+agg -> bf16 GEMM -> pre,stats -
template<int NOUT>
__global__ __launch_bounds__(256) void layer_kernel(
    const float* __restrict__ prev,      // [NROWS][64]
    const float* __restrict__ stats_in,  // 2048 (sums of prev)
    const float* __restrict__ gamma, const float* __restrict__ beta,
    const __bf16* __restrict__ wt,       // [NOUT][64]
    const float* __restrict__ bias,      // [NOUT]
    float* __restrict__ outp,            // [NROWS][NOUT]
    float* __restrict__ stats_out)       // 2048
{
    constexpr int KP = 72;
    __shared__ __align__(16) short sA[112*KP];
    __shared__ __align__(16) short sB[NOUT*KP];
    const int tid = threadIdx.x, wave = tid >> 6, lane = tid & 63;
    const int rowbase = blockIdx.x * 112;

    // stage B tile
    for (int i = tid; i < NOUT*8; i += 256) {
        int n = i >> 3, kk = (i & 7)*8;
        *reinterpret_cast<uint4*>(&sB[n*KP+kk]) =
            *reinterpret_cast<const uint4*>(wt + n*64 + kk);
    }
    // build A = chain_agg(relu(bn(prev))): thread owns 1 chain x 2 cols
    {
        const int ch = tid >> 5, c2 = (tid & 31)*2;
        float mu0 = stats_in[c2]*(1.f/NROWS);
        float v0  = stats_in[1024+c2]*(1.f/NROWS) - mu0*mu0;
        float a0  = gamma[c2]*rsqrtf(v0+BN_EPS), c0 = beta[c2]-mu0*a0;
        float mu1 = stats_in[c2+1]*(1.f/NROWS);
        float v1  = stats_in[1024+c2+1]*(1.f/NROWS) - mu1*mu1;
        float a1  = gamma[c2+1]*rsqrtf(v1+BN_EPS), c1 = beta[c2+1]-mu1*a1;
        float h0[14], h1[14];
        const float* src = prev + (size_t)(rowbase + ch*14)*64 + c2;
        #pragma unroll
        for (int r = 0; r < 14; ++r) {
            float2 v = *reinterpret_cast<const float2*>(src + r*64);
            h0[r] = fmaxf(a0*v.x + c0, 0.f);
            h1[r] = fmaxf(a1*v.y + c1, 0.f);
        }
        #pragma unroll
        for (int r = 0; r < 14; ++r) {
            float g0 = (r>0 ? h0[r-1] : 0.f) + (r<13 ? h0[r+1] : 0.f);
            float g1 = (r>0 ? h1[r-1] : 0.f) + (r<13 ? h1[r+1] : 0.f);
            union { __bf16 b[2]; unsigned u; } pk;
            pk.b[0] = (__bf16)g0; pk.b[1] = (__bf16)g1;
            *reinterpret_cast<unsigned*>(&sA[(ch*14+r)*KP + c2]) = pk.u;
        }
    }
    __syncthreads();

    const int m = lane & 15, q = lane >> 4;
    constexpr int NCH = NOUT/64;
    f32x4 acc[NCH][7];
    #pragma unroll
    for (int cc = 0; cc < NCH; ++cc)
        #pragma unroll
        for (int t = 0; t < 7; ++t) acc[cc][t] = (f32x4){0.f,0.f,0.f,0.f};

    #pragma unroll
    for (int ks = 0; ks < 64; ks += 32) {
        bf16x8 af[7];
        #pragma unroll
        for (int t = 0; t < 7; ++t)
            af[t] = *reinterpret_cast<const bf16x8*>(&sA[(t*16+m)*KP + ks + q*8]);
        #pragma unroll
        for (int cc = 0; cc < NCH; ++cc) {
            bf16x8 bf = *reinterpret_cast<const bf16x8*>(
                &sB[(cc*64 + wave*16 + m)*KP + ks + q*8]);
            #pragma unroll
            for (int t = 0; t < 7; ++t)
                acc[cc][t] = __builtin_amdgcn_mfma_f32_16x16x32_bf16(af[t], bf, acc[cc][t], 0, 0, 0);
        }
    }

    #pragma unroll
    for (int cc = 0; cc < NCH; ++cc) {
        const int ocol = cc*64 + wave*16 + m;
        const float bb = bias[ocol];
        float s = 0.f, s2 = 0.f;
        #pragma unroll
        for (int t = 0; t < 7; ++t)
            #pragma unroll
            for (int r = 0; r < 4; ++r) {
                float v = acc[cc][t][r] + bb;
                outp[(size_t)(rowbase + t*16 + q*4 + r)*NOUT + ocol] = v;
                s += v; s2 += v*v;
            }
        s  += __shfl_xor(s, 16);  s  += __shfl_xor(s, 32);
        s2 += __shfl_xor(s2, 16); s2 += __shfl_xor(s2, 32);
        if (lane < 16) {
            atomicAdd(&stats_out[ocol], s);
            atomicAdd(&stats_out[1024 + ocol], s2);
        }
    }
}

// ---------------- Layer 5 fused: BN+ReLU+agg + reg-A streamed-B + min/max --
__global__ __launch_bounds__(256, 2) void l5_kernel(
    const float* __restrict__ prev,      // [NROWS][128] (pre4)
    const float* __restrict__ stats_in,  // 2048
    const float* __restrict__ gamma, const float* __restrict__ beta,
    const __bf16* __restrict__ wtb,      // blocked W5, 131072 elems
    const float* __restrict__ bias,      // [1024]
    float* __restrict__ omax,            // [NB][1024]
    float* __restrict__ omin,            // [NB][1024]
    float* __restrict__ stats_out)       // 2048
{
    __shared__ __align__(16) short sA[15232];    // 112*136
    __shared__ __align__(16) short sB[2][8192];
    const int tid = threadIdx.x, wave = tid >> 6, lane = tid & 63;
    const int m = lane & 15, q = lane >> 4;
    const int rowbase = blockIdx.x * 112;

    // stage B chunk 0
    {
        const char* gB = (const char*)wtb;
        #pragma unroll
        for (int s4 = 0; s4 < 4; ++s4) {
            int seg = wave*4 + s4;
            gl_lds16(gB + seg*1024 + lane*16, (char*)sB[0] + seg*1024);
        }
    }
    // build A = chain_agg(relu(bn(pre4))): thread owns 1 chain x 4 cols
    {
        const int ch = tid >> 5, c4 = (tid & 31)*4;
        float aa[4], cc4[4];
        #pragma unroll
        for (int j = 0; j < 4; ++j) {
            float mu = stats_in[c4+j]*(1.f/NROWS);
            float vr = stats_in[1024+c4+j]*(1.f/NROWS) - mu*mu;
            aa[j] = gamma[c4+j]*rsqrtf(vr+BN_EPS);
            cc4[j] = beta[c4+j] - mu*aa[j];
        }
        float h[14][4];
        const float* src = prev + (size_t)(rowbase + ch*14)*128 + c4;
        #pragma unroll
        for (int r = 0; r < 14; ++r) {
            float4 v = *reinterpret_cast<const float4*>(src + r*128);
            h[r][0] = fmaxf(aa[0]*v.x + cc4[0], 0.f);
            h[r][1] = fmaxf(aa[1]*v.y + cc4[1], 0.f);
            h[r][2] = fmaxf(aa[2]*v.z + cc4[2], 0.f);
            h[r][3] = fmaxf(aa[3]*v.w + cc4[3], 0.f);
        }
        #pragma unroll
        for (int r = 0; r < 14; ++r) {
            union { __bf16 b[4]; uint2 u; } pk;
            #pragma unroll
            for (int j = 0; j < 4; ++j) {
                float g = (r>0 ? h[r-1][j] : 0.f) + (r<13 ? h[r+1][j] : 0.f);
                pk.b[j] = (__bf16)g;
            }
            *reinterpret_cast<uint2*>(&sA[(ch*14+r)*136 + c4]) = pk.u;
        }
    }
    __syncthreads();

    // A fragments -> registers
    bf16x8 af[7][4];
    #pragma unroll
    for (int t = 0; t < 7; ++t)
        #pragma unroll
        for (int kk = 0; kk < 4; ++kk)
            af[t][kk] = *reinterpret_cast<const bf16x8*>(&sA[(t*16 + m)*136 + kk*32 + q*8]);
    __syncthreads();   // all A reads done; sA becomes epilogue slabs

    float* slab = reinterpret_cast<float*>(sA) + wave*1904;  // [112][17] per wave
    float sacc[16], s2acc[16];
    #pragma unroll
    for (int c = 0; c < 16; ++c) { sacc[c] = 0.f; s2acc[c] = 0.f; }

    #pragma unroll 1
    for (int c = 0; c < 16; ++c) {
        if (c < 15) {
            const char* gB = (const char*)wtb + (c+1)*16384;
            char* lB = (char*)sB[(c+1) & 1];
            #pragma unroll
            for (int s4 = 0; s4 < 4; ++s4) {
                int seg = wave*4 + s4;
                gl_lds16(gB + seg*1024 + lane*16, lB + seg*1024);
            }
        }
        const short* bcur = sB[c & 1];
        f32x4 acc[7];
        #pragma unroll
        for (int t = 0; t < 7; ++t) acc[t] = (f32x4){0.f,0.f,0.f,0.f};
        #pragma unroll
        for (int k4 = 0; k4 < 4; ++k4) {
            bf16x8 bf = *reinterpret_cast<const bf16x8*>(
                &bcur[(k4*4 + q)*512 + (wave*16 + m)*8]);
            #pragma unroll
            for (int t = 0; t < 7; ++t)
                acc[t] = __builtin_amdgcn_mfma_f32_16x16x32_bf16(af[t][k4], bf, acc[t], 0, 0, 0);
        }
        const int ocol = c*64 + wave*16 + m;
        const float bb = bias[ocol];
        const int r0 = q*4;
        float s = 0.f, s2 = 0.f;
        #pragma unroll
        for (int t = 0; t < 7; ++t)
            #pragma unroll
            for (int r = 0; r < 4; ++r) {
                float v = acc[t][r] + bb;
                s += v; s2 += v*v;
                slab[(t*16 + r0 + r)*17 + m] = v;
            }
        s  += __shfl_xor(s, 16);  s  += __shfl_xor(s, 32);
        s2 += __shfl_xor(s2, 16); s2 += __shfl_xor(s2, 32);
        sacc[c] = s; s2acc[c] = s2;          // registers, no atomics here
        // chain min/max from wave-private slab (no barrier needed: same wave)
        #pragma unroll
        for (int pi = 0; pi < 2; ++pi) {
            int ch  = (lane + 64*pi) >> 4;
            int col = lane & 15;
            float mx = -3.4e38f, mn = 3.4e38f;
            #pragma unroll
            for (int p = 0; p < PLEN; ++p) {
                float v = slab[(ch*PLEN + p)*17 + col];
                mx = fmaxf(mx, v); mn = fminf(mn, v);
            }
            size_t off = (size_t)(blockIdx.x*8 + ch)*1024 + c*64 + wave*16 + col;
            omax[off] = mx; omin[off] = mn;
        }
        __syncthreads();   // B double-buffer protection + DMA drain
    }

    if (lane < 16) {
        #pragma unroll
        for (int c = 0; c < 16; ++c) {
            int ocol = c*64 + wave*16 + lane;
            atomicAdd(&stats_out[ocol], sacc[c]);
            atomicAdd(&stats_out[1024 + ocol], s2acc[c]);
        }
    }
}

// ---------------- head+cluster fused: one block per batch row -------------
__global__ __launch_bounds__(256) void headclu_kernel(
    const float* __restrict__ omax, const float* __restrict__ omin,
    const float* __restrict__ stats,
    const float* __restrict__ gamma, const float* __restrict__ beta,
    const float* __restrict__ embW, const float* __restrict__ embB,
    const float* __restrict__ cluW,
    float* __restrict__ e,            // [NB][10]
    float* __restrict__ cOut,         // [NB][800]
    float* __restrict__ dOut,         // or null
    const float* __restrict__ eOther, // e1 or null
    float* __restrict__ simOut)       // or null
{
    const int b = blockIdx.x, tid = threadIdx.x;
    const int wave = tid >> 6, lane = tid & 63;
    float acc[10];
    #pragma unroll
    for (int j = 0; j < 10; ++j) acc[j] = 0.f;
    #pragma unroll
    for (int i = 0; i < 4; ++i) {
        int k = tid + i*256;
        float mu  = stats[k]*(1.f/NROWS);
        float var = stats[1024+k]*(1.f/NROWS) - mu*mu;
        float a = gamma[k]*rsqrtf(var+BN_EPS);
        float c = beta[k] - mu*a;
        float v = (a >= 0.f) ? omax[(size_t)b*1024 + k] : omin[(size_t)b*1024 + k];
        float h = fmaxf(a*v + c, 0.f);
        #pragma unroll
        for (int j = 0; j < 10; ++j) acc[j] += h * embW[k*10 + j];
    }
    #pragma unroll
    for (int j = 0; j < 10; ++j) {
        acc[j] += __shfl_down(acc[j], 32);
        acc[j] += __shfl_down(acc[j], 16);
        acc[j] += __shfl_down(acc[j], 8);
        acc[j] += __shfl_down(acc[j], 4);
        acc[j] += __shfl_down(acc[j], 2);
        acc[j] += __shfl_down(acc[j], 1);
    }
    __shared__ float red[4][10];
    __shared__ float se[10];
    if (lane == 0)
        #pragma unroll
        for (int j = 0; j < 10; ++j) red[wave][j] = acc[j];
    __syncthreads();
    if (tid < 10) {
        float t = red[0][tid]+red[1][tid]+red[2][tid]+red[3][tid] + embB[tid];
        se[tid] = t;
        e[b*10 + tid] = t;
    }
    __syncthreads();

    float ev[10];
    #pragma unroll
    for (int j = 0; j < 10; ++j) ev[j] = se[j];
    float dloc[4], qloc[4], qs = 0.f;
    #pragma unroll
    for (int i = 0; i < 4; ++i) {
        int mm = tid + i*256;
        float dd = 0.f;
        if (mm < 800) {
            #pragma unroll
            for (int j = 0; j < 10; ++j) { float t = ev[j] - cluW[mm*10 + j]; dd += t*t; }
        }
        dloc[i] = dd;
        float qv = (mm < 800) ? 1.f/(1.f + dd) : 0.f;
        qloc[i] = qv; qs += qv;
    }
    float t = qs;
    t += __shfl_down(t,32); t += __shfl_down(t,16); t += __shfl_down(t,8);
    t += __shfl_down(t,4);  t += __shfl_down(t,2);  t += __shfl_down(t,1);
    __shared__ float sred[4];
    if (lane == 0) sred[wave] = t;
    __syncthreads();
    float inv = 1.f / (sred[0]+sred[1]+sred[2]+sred[3]);
    #pragma unroll
    for (int i = 0; i < 4; ++i) {
        int mm = tid + i*256;
        if (mm < 800) {
            cOut[(size_t)b*800 + mm] = qloc[i]*inv;
            if (dOut) dOut[(size_t)b*800 + mm] = dloc[i];
        }
    }
    if (simOut && tid == 0) {
        float ss = 0.f;
        #pragma unroll
        for (int j = 0; j < 10; ++j) {
            float df = eOther[b*10 + j] - se[j] + 1e-6f;
            ss += df*df;
        }
        simOut[b] = sqrtf(ss);
    }
}

// ---------------------------------------------------------------------------
extern "C" void kernel_launch(void* const* d_in, const int* in_sizes, int n_in,
                              void* d_out, int out_size, void* d_ws, size_t ws_size,
                              hipStream_t stream)
{
    const float* x[2] = {(const float*)d_in[0], (const float*)d_in[1]};
    const float *W[5], *bi[5], *ga[5], *be[5];
    for (int l = 0; l < 5; l++) {
        W[l]  = (const float*)d_in[2 + 4*l];
        bi[l] = (const float*)d_in[3 + 4*l];
        ga[l] = (const float*)d_in[4 + 4*l];
        be[l] = (const float*)d_in[5 + 4*l];
    }
    const float* embW = (const float*)d_in[22];
    const float* embB = (const float*)d_in[23];
    const float* cluW = (const float*)d_in[24];
    float* out = (float*)d_out;
    float* ws  = (float*)d_ws;

    // workspace (floats): preA 7.34M | preB 7.34M | omin 4.19M | stats 20480 | weights
    float*  preA  = ws;
    float*  preB  = ws + 7340032;
    float*  omax  = preA;                    // preA is dead during l5/head
    float*  omin  = ws + 14680064;
    float*  stats = ws + 18874368;
    __bf16* wt2   = (__bf16*)(ws + 18894848);
    __bf16* wt3   = wt2 + 4096;
    __bf16* wt4   = wt2 + 8192;
    __bf16* wt5b  = wt2 + 16384;

    wprep_kernel<<<656, 256, 0, stream>>>(W[1], W[2], W[3], W[4],
                                          wt2, wt3, wt4, wt5b, stats);

    float* simO = out;
    float* c1O  = out + 4096;
    float* c2O  = out + 3280896;
    float* e1O  = out + 6557696;
    float* e2O  = out + 6598656;
    float* d1O  = out + 6639616;

    for (int inp = 0; inp < 2; inp++) {
        float* st = stats + inp*5*2048;
        l1_kernel<<<NB/4, 256, 0, stream>>>(x[inp], W[0], bi[0], preA, st);
        layer_kernel<64><<<NROWS/112, 256, 0, stream>>>(
            preA, st, ga[0], be[0], wt2, bi[1], preB, st + 2048);
        layer_kernel<64><<<NROWS/112, 256, 0, stream>>>(
            preB, st + 2048, ga[1], be[1], wt3, bi[2], preA, st + 4096);
        layer_kernel<128><<<NROWS/112, 256, 0, stream>>>(
            preA, st + 4096, ga[2], be[2], wt4, bi[3], preB, st + 6144);
        l5_kernel<<<NROWS/112, 256, 0, stream>>>(
            preB, st + 6144, ga[3], be[3], wt5b, bi[4], omax, omin, st + 8192);
        headclu_kernel<<<NB, 256, 0, stream>>>(
            omax, omin, st + 8192, ga[4], be[4], embW, embB, cluW,
            (inp == 0) ? e1O : e2O,
            (inp == 0) ? c1O : c2O,
            (inp == 0) ? d1O : nullptr,
            (inp == 0) ? nullptr : e1O,
            (inp == 0) ? nullptr : simO);
    }
}